// Round 4
// baseline (69.902 us; speedup 1.0000x reference)
//
#include <hip/hip_runtime.h>
#include <math.h>

// Problem constants (fixed by setup_inputs)
constexpr int BB = 512;    // batch (GEMM M)
constexpr int DD = 512;    // features (GEMM K)
constexpr int CC = 1000;   // classes
constexpr int CP = 1024;   // padded classes (GEMM N)
constexpr int RP = 528;    // padded row length (shorts): 1056 B, 16B-aligned,
                           // breaks 256B/1KB channel periodicity
constexpr float EPSF = 0.3f;

// TWO launches (R8 structure — best measured; coop-sync single kernel was a
// 2.5x regression: grid.sync() costs ~125 us on 8-XCD gfx950).
// K[b,c]^2 = nj[b] + nc[c] - 2*dot(col_jb, col_c); dot via bf16 MFMA.
//
// R13 changes:
//   - split-K reverted (R12 was noise-neutral; its pacc LDS round-trip sat on
//     the epilogue critical path for nothing). Back to 512x256, 1 tile/wave.
//   - SWAPPED-OPERAND MFMA: mfma(class_frag, batch_frag) -> C^T layout, so
//     each lane owns (batch row fr) x (4 consecutive classes quad*4+r):
//       * y tile: one aligned float4 per lane (was 4 scalar loads)
//       * nj/ymax: direct per-lane loads, zero __shfl broadcasts
//       * nc: 8 hoisted float4 partial loads (normp[dc][c] layout, vectorized
//         over classes), summed in-register
//       * row-max: 3 in-register fmax + TWO __shfl_xor (was 16 butterflies)
//   - all epilogue operand loads hoisted above the fragment loads so their
//     latency hides under the 32 fragment loads + 16 MFMAs.
//
// ws layout (16B-aligned):
//   Wt    [1024*528] ushort @ 0        (1081 KB)
//   normp [8*1024]   float  @ 1088 KB  (32 KB, partials [dc][c])
//   wj    [512]      int    @ +32 KB
//   wymax [512]      float  @ +2 KB

using short8 = __attribute__((ext_vector_type(8))) short;
using us8    = __attribute__((ext_vector_type(8))) unsigned short;
using f32x4  = __attribute__((ext_vector_type(4))) float;

__device__ inline unsigned short f2bf(float f) {   // RNE float->bf16
  unsigned u = __float_as_uint(f);
  return (unsigned short)((u + 0x7FFFu + ((u >> 16) & 1u)) >> 16);
}

__global__ __launch_bounds__(256) void lm_build(const float* __restrict__ y,
                                                const float* __restrict__ kW,
                                                unsigned short* __restrict__ Wt,
                                                float* __restrict__ normp,
                                                int* __restrict__ wj,
                                                float* __restrict__ wymax,
                                                float* __restrict__ out) {
  const int t = threadIdx.x;
  const int w = t >> 6, lane = t & 63;

  if (blockIdx.x < 128) {
    // ---------- argmax/ymax, one wave per row, + fused y->out copy ----------
    const int b = blockIdx.x * 4 + w;
    const float* yr = y + (size_t)b * CC;
    float bv = -INFINITY; int bi = 0;
    #pragma unroll
    for (int k = 0; k < 4; ++k) {
      const int c4 = (lane + k * 64) * 4;   // ascending per lane -> '>' keeps lowest
      if (c4 < CC) {
        const float4 v = *(const float4*)(yr + c4);
        if (v.x > bv) { bv = v.x; bi = c4; }
        if (v.y > bv) { bv = v.y; bi = c4 + 1; }
        if (v.z > bv) { bv = v.z; bi = c4 + 2; }
        if (v.w > bv) { bv = v.w; bi = c4 + 3; }
        float* orow = out + (size_t)b * (CC + 1) + c4;  // scalar stores (row stride 1001)
        orow[0] = v.x; orow[1] = v.y; orow[2] = v.z; orow[3] = v.w;
      }
    }
    #pragma unroll
    for (int off = 32; off > 0; off >>= 1) {
      const float ov = __shfl_down(bv, off);
      const int   oi = __shfl_down(bi, off);
      if (ov > bv || (ov == bv && oi < bi)) { bv = ov; bi = oi; }
    }
    if (lane == 0) { wj[b] = bi; wymax[b] = bv; }
  } else {
    // ---------- transpose kW -> Wt (LDS-staged) + fp32 norm partials ----------
    __shared__ float nsum[4][64];
    __shared__ __align__(16) unsigned short tile[64][72];  // 64c x 64d staging (+pad)
    const int blk = blockIdx.x - 128;    // 0..127
    const int cs = blk & 15, dc = blk >> 4;   // 16 c-slices x 8 d-chunks
    const int c0 = cs * 64, d0 = dc * 64;
    const int c = c0 + lane;
    const bool cok = (c < CC);
    float s = 0.f;
    #pragma unroll 8
    for (int it = 0; it < 16; ++it) {
      const int dd = w + it * 4;                    // 0..63
      const float v = cok ? kW[(size_t)(d0 + dd) * CC + c] : 0.f;
      s += v * v;
      tile[lane][dd] = f2bf(v);
    }
    nsum[w][lane] = s;
    __syncthreads();
    if (w == 0)   // partial layout: normp[dc][c] (pads write 0)
      normp[(size_t)dc * CP + c] =
          nsum[0][lane] + nsum[1][lane] + nsum[2][lane] + nsum[3][lane];
    // coalesced 16B writes of the transposed tile
    #pragma unroll
    for (int k = 0; k < 2; ++k) {
      const int lin = t * 2 + k;                    // 0..511
      const int cc = lin >> 3, ch = lin & 7;
      *(us8*)(Wt + (size_t)(c0 + cc) * RP + d0 + ch * 8) =
          *(const us8*)(&tile[cc][ch * 8]);
    }
  }
}

__global__ __launch_bounds__(256) void lm_gemm(const unsigned short* __restrict__ Wt,
                                               const float* __restrict__ y,
                                               const float* __restrict__ normp,
                                               const int* __restrict__ wj,
                                               const float* __restrict__ wymax,
                                               float* __restrict__ out) {
  __shared__ float sh[4][16];          // per-block row-max combine (4 waves x 16 rows)
  const int t = threadIdx.x;
  const int lane = t & 63;
  const int w = t >> 6;
  const int tile = blockIdx.x * 4 + w;          // 0..2047
  const int m0 = (tile >> 6) * 16;              // block-uniform (4 consecutive tiles)
  const int n0 = (tile & 63) * 16;

  const int fr = lane & 15;            // batch row (C^T: col=lane&15)
  const int quad = lane >> 4;          // classes quad*4+reg (C^T: row=quad*4+reg)

  const int row = m0 + fr;             // this lane's batch row
  const int ja = wj[row];              // dependent-chain head: hoisted first
  const float ym = wymax[row];

  const int cb0 = n0 + quad * 4;       // this lane's 4-class base
  const int cb = (cb0 <= CC - 4) ? cb0 : CC - 4;   // clamp: OOB tiles fully masked below
  const f32x4 y4 = *(const f32x4*)(y + (size_t)row * CC + cb);

  // norms: nj (column j of this batch row) + nc4 (4 consecutive classes)
  float nj = 0.f;
  f32x4 nc4 = {0.f, 0.f, 0.f, 0.f};
  #pragma unroll
  for (int dc = 0; dc < 8; ++dc) {
    nj  += normp[(size_t)dc * CP + ja];
    nc4 += *(const f32x4*)(normp + (size_t)dc * CP + cb);
  }

  const unsigned short* ap = Wt + (size_t)ja * RP + quad * 8;         // batch (gathered)
  const unsigned short* bp = Wt + (size_t)(n0 + fr) * RP + quad * 8;  // classes

  // register-prefetch the whole K-slab (32 independent 16B loads), then MFMA
  short8 af[16], bf[16];
  #pragma unroll
  for (int k = 0; k < 16; ++k) {
    af[k] = *(const short8*)(ap + k * 32);
    bf[k] = *(const short8*)(bp + k * 32);
  }
  // SWAPPED operands: first=classes, second=batch -> C^T lane layout
  f32x4 acc0 = {0.f, 0.f, 0.f, 0.f};
  f32x4 acc1 = {0.f, 0.f, 0.f, 0.f};
  #pragma unroll
  for (int k = 0; k < 8; ++k) {
    acc0 = __builtin_amdgcn_mfma_f32_16x16x32_bf16(bf[2 * k],     af[2 * k],     acc0, 0, 0, 0);
    acc1 = __builtin_amdgcn_mfma_f32_16x16x32_bf16(bf[2 * k + 1], af[2 * k + 1], acc1, 0, 0, 0);
  }

  // ---- lane-local epilogue: 4 candidates, zero broadcasts ----
  float cdm = -INFINITY;
  #pragma unroll
  for (int r = 0; r < 4; ++r) {
    if (cb0 + r < CC) {                // class validity (cb==cb0 whenever any valid)
      const float k2 = nj + nc4[r] - 2.f * (acc0[r] + acc1[r]);
      const float yv = y4[r];
      const float cd = (yv == ym) ? -INFINITY
                                  : yv + EPSF * sqrtf(fmaxf(k2, 0.f) + 1e-10f);
      cdm = fmaxf(cdm, cd);
    }
  }
  // combine the 4 quads (same fr = same batch row): 2 shuffles
  cdm = fmaxf(cdm, __shfl_xor(cdm, 16));
  cdm = fmaxf(cdm, __shfl_xor(cdm, 32));
  if (lane < 16) sh[w][fr] = cdm;
  __syncthreads();
  if (t < 16) {                        // combine 4 waves -> 16 atomics per block
    const float m = fmaxf(fmaxf(sh[0][t], sh[1][t]), fmaxf(sh[2][t], sh[3][t]));
    // positive floats: int compare == float compare (validated R5-R8);
    // -inf candidates map to very-negative int -> never win, also safe
    atomicMax((int*)(out + (size_t)(m0 + t) * (CC + 1) + CC), __float_as_int(m));
  }
}

extern "C" void kernel_launch(void* const* d_in, const int* in_sizes, int n_in,
                              void* d_out, int out_size, void* d_ws, size_t ws_size,
                              hipStream_t stream) {
  const float* y  = (const float*)d_in[0];   // [512, 1000]
  const float* kW = (const float*)d_in[1];   // [512, 1000]
  float* out = (float*)d_out;                // [512, 1001]

  char* ws = (char*)d_ws;
  unsigned short* Wt = (unsigned short*)(ws);                   // 1024*528*2 = 1081 KB
  float* normp       = (float*)(ws + (1088 << 10));             // 32 KB (partials [dc][c])
  int*   wjp         = (int*)(ws + (1120 << 10));               // 2 KB
  float* wymaxp      = (float*)(ws + (1122 << 10));             // 2 KB

  lm_build<<<256, 256, 0, stream>>>(y, kW, Wt, normp, wjp, wymaxp, out);
  lm_gemm<<<512, 256, 0, stream>>>(Wt, y, normp, wjp, wymaxp, out);
}